// Round 11
// baseline (780.526 us; speedup 1.0000x reference)
//
#include <hip/hip_runtime.h>
#include <cstddef>

// Problem constants (B=4096, H=1024, L=4)
#define BATCH 4096
#define HID   1024
#define NLAY  4
#define NG    4096   // 4*H  (gate rows of W)
#define KTOT  2048   // 2*H  (concat [x|h] contraction dim)
#define BH    (BATCH * HID)   // 4,194,304
#define NT    (KTOT / 64)     // 32 K-tiles

typedef short short8 __attribute__((ext_vector_type(8)));   // 8 bf16 in 4 VGPRs
typedef float f32x4  __attribute__((ext_vector_type(4)));

// fp32 -> bf16 round-to-nearest-even (inputs finite; no NaN handling needed)
__device__ __forceinline__ unsigned short f2bf(float f) {
    union { float f; unsigned u; } v; v.f = f;
    unsigned r = v.u + 0x7fffu + ((v.u >> 16) & 1u);
    return (unsigned short)(r >> 16);
}

__device__ __forceinline__ float sigm_f(float x) {
    return 1.0f / (1.0f + __expf(-x));
}
__device__ __forceinline__ float tanh_f(float x) {
    float e = __expf(-2.0f * fabsf(x));
    float r = (1.0f - e) / (1.0f + e);
    return copysignf(r, x);
}

// async global->LDS, 16B per lane. LDS dest is wave-uniform base + lane*16.
#define GLOAD_LDS16(g, l)                                                            \
    __builtin_amdgcn_global_load_lds(                                                \
        (const __attribute__((address_space(1))) void*)(g),                          \
        (__attribute__((address_space(3))) void*)(l), 16, 0, 0)

// ---------------------------------------------------------------------------
// Prep kernels: byte-identical to the round-7 HW-verified versions.
// ---------------------------------------------------------------------------
__global__ __launch_bounds__(256) void prep_weights(
    const float* __restrict__ Wih, const float* __restrict__ Whh,
    unsigned short* __restrict__ Wb)
{
    size_t t    = (size_t)blockIdx.x * 256 + threadIdx.x;
    size_t base = t * 4;
    size_t row  = base >> 11;
    int    k    = (int)(base & (KTOT - 1));
    const float* src = (k < HID) ? (Wih + row * HID + k)
                                 : (Whh + row * HID + (k - HID));
    float4 v = *(const float4*)src;
    ushort4 o; o.x = f2bf(v.x); o.y = f2bf(v.y); o.z = f2bf(v.z); o.w = f2bf(v.w);
    *(ushort4*)(Wb + base) = o;
}

__global__ __launch_bounds__(256) void prep_bias(
    const float* __restrict__ bih, const float* __restrict__ bhh,
    float* __restrict__ bias)
{
    int i = blockIdx.x * 256 + threadIdx.x;
    bias[i] = bih[i] + bhh[i];
}

__global__ __launch_bounds__(256) void prep_misc(
    const float* __restrict__ x, const float* __restrict__ h0,
    const float* __restrict__ c0,
    unsigned short* __restrict__ A0, unsigned short* __restrict__ A1,
    unsigned short* __restrict__ A2, unsigned short* __restrict__ A3,
    float* __restrict__ cc)
{
    int idx = blockIdx.x * 256 + threadIdx.x;
    int b = idx >> 10, h = idx & (HID - 1);
    float4 hv = *(const float4*)(h0 + (size_t)idx * NLAY);
    A0[(size_t)b * KTOT + h]       = f2bf(x[idx]);
    A0[(size_t)b * KTOT + HID + h] = f2bf(hv.x);
    A1[(size_t)b * KTOT + HID + h] = f2bf(hv.y);
    A2[(size_t)b * KTOT + HID + h] = f2bf(hv.z);
    A3[(size_t)b * KTOT + HID + h] = f2bf(hv.w);
    float4 cv = *(const float4*)(c0 + (size_t)idx * NLAY);
    cc[idx]          = cv.x;
    cc[BH + idx]     = cv.y;
    cc[2 * BH + idx] = cv.z;
    cc[3 * BH + idx] = cv.w;
}

// ---------------------------------------------------------------------------
// 8-phase 256x256 fused GEMM+LSTM (T2+T3+T4+T5 on the verified gate-permuted,
// layer-major-epilogue structure).
//
// Geometry: BM=256 (batch) x BN=256 (gate cols) x BK=64; 8 waves (wm in {0,1}
// owns 128 rows, wn in {0..3} owns 64 cols); per-wave 8m x 4n fragments of
// 16x16; frag n == gate n for h = bn*64 + wn*16 + lane15 (c>>4 = wn*4+n).
//
// LDS: ldsA[2 buf][2 half][128][64], ldsB same; 128 KiB total. T2 XOR-swizzle
// carried verbatim from the verified kernel (phys slot = logical ^ (row&7);
// linear gload dest + swizzled global source + swizzled ds_read).
//
// Schedule (group u = 4 phases, computes tile u from buf[u&1]):
//   p0: read 8 B-frags (held in regs all group) + A-frags m0,m1;
//       stage A-half0(u+1) -> buf[u+1&1]   [dead since group u-1 p3 barrier]
//   p1: read A m2,m3; stage A-half1(u+1)
//   p2: read A m4,m5; stage B-half0(u+2) -> buf[u&1]  [B(u) dead since p0]
//   p3: read A m6,m7; stage B-half1(u+2); s_waitcnt vmcnt(4)
//       [leaves only B(u+2)'s 2 halves in flight; tile u+1 guaranteed landed;
//        tail u>=NT-2: vmcnt(0)]
//   each phase: ...; s_barrier; setprio(1); 16 MFMA; setprio(0); s_barrier
// Prologue stages tile0 + B(1) (6 halves = 12 loads), vmcnt(4), barrier.
// ds_reads are plain C++ derefs -> compiler inserts exact lgkmcnt before MFMA;
// compiler memory-fences around each raw s_barrier pin cross-phase ordering.
// vmcnt ledger (audited r8/r9): steady-state 12 outstanding at p3; vmcnt(4)
// retires exactly tile u+1's 8; tail drains via vmcnt(0) before final reads.
// Address-map round-trip + cross-wave staging hazards re-audited r9; barrier
// uniformity + compiler-interaction (raw s_barrier carries no implicit
// vmcnt-drain; asm memory fences pin gload_lds issue order) audited r10.
// ---------------------------------------------------------------------------
#define FENCE() asm volatile("" ::: "memory")
#define BARRIER() do { FENCE(); __builtin_amdgcn_s_barrier(); FENCE(); } while (0)

__global__ __launch_bounds__(512, 1) void gemm_lstm_8ph(
    const unsigned short* __restrict__ A,   // [BATCH][KTOT] bf16
    const unsigned short* __restrict__ W,   // [NG][KTOT] bf16, this layer
    const float* __restrict__ bias,         // [NG] (bih+bhh)
    const float* cin,                       // cc_l [BH]   (aliases cout)
    float* cout,                            // cc_l [BH]
    float* __restrict__ hout,               // hT_l [BH]
    unsigned short* __restrict__ Anext)     // next layer A panel or nullptr
{
    __shared__ unsigned short ldsA[2 * 2 * 128 * 64];   // 64 KiB
    __shared__ unsigned short ldsB[2 * 2 * 128 * 64];   // 64 KiB

    const int tid  = threadIdx.x;
    const int wid  = tid >> 6;
    const int lane = tid & 63;
    const int wm = wid >> 2, wn = wid & 3;
    const int bn = blockIdx.x, bm = blockIdx.y;

    f32x4 acc[8][4] = {};

    // --- staging addressing: 512 threads cover 64 rows x 64 cols per call ---
    const int srow  = tid >> 3;                         // 0..63
    const int sswz  = ((tid & 7) ^ (srow & 7)) << 3;    // swizzled source col (elems)
    const int dLds  = srow * 64 + (tid & 7) * 8;        // linear dest (== tid*16B)
    const unsigned short* Ag = A + (size_t)(bm * 256 + srow) * KTOT + sswz;
    const unsigned short* Wg[2][2];
#pragma unroll
    for (int half = 0; half < 2; ++half)
#pragma unroll
        for (int j = 0; j < 2; ++j) {
            int s    = half * 128 + j * 64 + srow;      // block-col 0..255
            int wrow = ((s >> 4) & 3) * HID + bn * 64 + ((s >> 6) & 3) * 16 + (s & 15);
            Wg[half][j] = W + (size_t)wrow * KTOT + sswz;
        }

#define STG_A(buf, half, kt) do {                                                     \
    GLOAD_LDS16(Ag + (size_t)((half) * 128) * KTOT + (size_t)(kt) * 64,               \
                &ldsA[(buf) * 16384 + (half) * 8192 + dLds]);                         \
    GLOAD_LDS16(Ag + (size_t)((half) * 128 + 64) * KTOT + (size_t)(kt) * 64,          \
                &ldsA[(buf) * 16384 + (half) * 8192 + 4096 + dLds]); } while (0)
#define STG_B(buf, half, kt) do {                                                     \
    GLOAD_LDS16(Wg[half][0] + (size_t)(kt) * 64,                                      \
                &ldsB[(buf) * 16384 + (half) * 8192 + dLds]);                         \
    GLOAD_LDS16(Wg[half][1] + (size_t)(kt) * 64,                                      \
                &ldsB[(buf) * 16384 + (half) * 8192 + 4096 + dLds]); } while (0)

    // --- fragment read addressing (T2 swizzle: slot ^ (row&7), row&7==lane&7) ---
    const int rrow = lane & 15;
    const int rkey = lane & 7;
    const int ro0  = (((lane >> 4) + 0) ^ rkey) << 3;   // kk=0 slot (elems)
    const int ro1  = (((lane >> 4) + 4) ^ rkey) << 3;   // kk=1 slot
    const int aB   = wm * 8192 + rrow * 64;             // + m*1024 + ro
    const int bB   = (wn >> 1) * 8192 + ((wn & 1) * 64 + rrow) * 64;  // + n*1024 + ro

#define LDA(cb, m, kk) (*(const short8*)&ldsA[(cb) + aB + (m) * 1024 + ((kk) ? ro1 : ro0)])
#define LDB(cb, n, kk) (*(const short8*)&ldsB[(cb) + bB + (n) * 1024 + ((kk) ? ro1 : ro0)])

#define MFMA_PAIR(m0_)                                                                \
    do {                                                                              \
        __builtin_amdgcn_s_setprio(1);                                                \
        _Pragma("unroll")                                                             \
        for (int n = 0; n < 4; ++n) {                                                 \
            acc[m0_][n]     = __builtin_amdgcn_mfma_f32_16x16x32_bf16(                \
                af[0][0], bf[n][0], acc[m0_][n], 0, 0, 0);                            \
            acc[m0_][n]     = __builtin_amdgcn_mfma_f32_16x16x32_bf16(                \
                af[0][1], bf[n][1], acc[m0_][n], 0, 0, 0);                            \
            acc[m0_ + 1][n] = __builtin_amdgcn_mfma_f32_16x16x32_bf16(                \
                af[1][0], bf[n][0], acc[m0_ + 1][n], 0, 0, 0);                        \
            acc[m0_ + 1][n] = __builtin_amdgcn_mfma_f32_16x16x32_bf16(                \
                af[1][1], bf[n][1], acc[m0_ + 1][n], 0, 0, 0);                        \
        }                                                                             \
        __builtin_amdgcn_s_setprio(0);                                                \
    } while (0)

    // --- prologue: tile0 (A0,A1,B0,B1) + B halves of tile1; vmcnt(4) ---
    STG_A(0, 0, 0); STG_A(0, 1, 0);
    STG_B(0, 0, 0); STG_B(0, 1, 0);
    STG_B(1, 0, 1); STG_B(1, 1, 1);
    asm volatile("s_waitcnt vmcnt(4)" ::: "memory");
    BARRIER();

    for (int u = 0; u < NT; ++u) {
        const int cur = u & 1, nxt = cur ^ 1;
        const int cA = cur * 16384;
        short8 bf[4][2];
        // ---- phase 0: B-frags (all, reg-held) + A m0,m1; stage A-half0(u+1)
        {
            short8 af[2][2];
#pragma unroll
            for (int n = 0; n < 4; ++n) { bf[n][0] = LDB(cA, n, 0); bf[n][1] = LDB(cA, n, 1); }
            af[0][0] = LDA(cA, 0, 0); af[0][1] = LDA(cA, 0, 1);
            af[1][0] = LDA(cA, 1, 0); af[1][1] = LDA(cA, 1, 1);
            if (u + 1 < NT) STG_A(nxt, 0, u + 1);
            BARRIER();
            MFMA_PAIR(0);
            BARRIER();
        }
        // ---- phase 1: A m2,m3; stage A-half1(u+1)
        {
            short8 af[2][2];
            af[0][0] = LDA(cA, 2, 0); af[0][1] = LDA(cA, 2, 1);
            af[1][0] = LDA(cA, 3, 0); af[1][1] = LDA(cA, 3, 1);
            if (u + 1 < NT) STG_A(nxt, 1, u + 1);
            BARRIER();
            MFMA_PAIR(2);
            BARRIER();
        }
        // ---- phase 2: A m4,m5; stage B-half0(u+2)
        {
            short8 af[2][2];
            af[0][0] = LDA(cA, 4, 0); af[0][1] = LDA(cA, 4, 1);
            af[1][0] = LDA(cA, 5, 0); af[1][1] = LDA(cA, 5, 1);
            if (u + 2 < NT) STG_B(cur, 0, u + 2);
            BARRIER();
            MFMA_PAIR(4);
            BARRIER();
        }
        // ---- phase 3: A m6,m7; stage B-half1(u+2); counted vmcnt
        {
            short8 af[2][2];
            af[0][0] = LDA(cA, 6, 0); af[0][1] = LDA(cA, 6, 1);
            af[1][0] = LDA(cA, 7, 0); af[1][1] = LDA(cA, 7, 1);
            if (u + 2 < NT) STG_B(cur, 1, u + 2);
            if (u < NT - 2) { asm volatile("s_waitcnt vmcnt(4)" ::: "memory"); }
            else            { asm volatile("s_waitcnt vmcnt(0)" ::: "memory"); }
            BARRIER();
            MFMA_PAIR(6);
            BARRIER();
        }
    }

    // --- fused LSTM epilogue (layer-major I/O; frag n == gate n; m89 C/D) ---
    const int h = bn * 64 + wn * 16 + (lane & 15);
    float bv[4];
#pragma unroll
    for (int n = 0; n < 4; ++n) bv[n] = bias[n * HID + h];

#pragma unroll
    for (int m = 0; m < 8; ++m) {
        const int b0 = bm * 256 + wm * 128 + m * 16 + ((lane >> 4) << 2);
#pragma unroll
        for (int r = 0; r < 4; ++r) {
            const int b = b0 + r;
            const size_t idx2 = (size_t)b * HID + h;
            float iv = sigm_f(acc[m][0][r] + bv[0]);
            float fv = sigm_f(acc[m][1][r] + bv[1]);
            float gv = tanh_f(acc[m][2][r] + bv[2]);
            float ov = sigm_f(acc[m][3][r] + bv[3]);
            float c2 = fv * cin[idx2] + iv * gv;    // in-place same-thread RMW
            float h2 = ov * tanh_f(c2);
            cout[idx2] = c2;
            hout[idx2] = h2;
            if (Anext) Anext[(size_t)b * KTOT + h] = f2bf(h2);
        }
    }
}

// ---------------------------------------------------------------------------
// Final interleave: layer-major hT/cc -> [B,H,L] float4-coalesced outputs.
// ---------------------------------------------------------------------------
__global__ __launch_bounds__(256) void interleave(
    const float* __restrict__ hT, const float* __restrict__ cc,
    float* __restrict__ outH, float* __restrict__ outC)
{
    int idx = blockIdx.x * 256 + threadIdx.x;
    float4 hv = { hT[idx], hT[BH + idx], hT[2 * BH + idx], hT[3 * BH + idx] };
    float4 cv = { cc[idx], cc[BH + idx], cc[2 * BH + idx], cc[3 * BH + idx] };
    *(float4*)(outH + (size_t)idx * NLAY) = hv;
    *(float4*)(outC + (size_t)idx * NLAY) = cv;
}

// ---------------------------------------------------------------------------
// Launch. ws layout identical to round 7 (268,500,992 B; proven available):
//   [0)           Wb     67,108,864
//   [67108864)    bias       65,536
//   [67174400)    A0..A3 67,108,864
//   [134283264)   cc     67,108,864   (c0 in, c2 out, in place)
//   [201392128)   hT     67,108,864
// ---------------------------------------------------------------------------
extern "C" void kernel_launch(void* const* d_in, const int* in_sizes, int n_in,
                              void* d_out, int out_size, void* d_ws, size_t ws_size,
                              hipStream_t stream)
{
    const float* x   = (const float*)d_in[0];
    const float* h0  = (const float*)d_in[1];
    const float* c0  = (const float*)d_in[2];
    const float* Wih = (const float*)d_in[3];
    const float* Whh = (const float*)d_in[4];
    const float* bih = (const float*)d_in[5];
    const float* bhh = (const float*)d_in[6];

    float* outH = (float*)d_out;
    float* outC = outH + (size_t)BH * NLAY;

    char* ws = (char*)d_ws;
    unsigned short* Wb   = (unsigned short*)(ws);
    float*          bias = (float*)(ws + 67108864);
    unsigned short* Ap[4];
    Ap[0] = (unsigned short*)(ws + 67174400);
    Ap[1] = (unsigned short*)(ws + 83951616);
    Ap[2] = (unsigned short*)(ws + 100728832);
    Ap[3] = (unsigned short*)(ws + 117506048);
    float* cc = (float*)(ws + 134283264);
    float* hT = (float*)(ws + 201392128);

    prep_weights<<<32768, 256, 0, stream>>>(Wih, Whh, Wb);
    prep_bias<<<64, 256, 0, stream>>>(bih, bhh, bias);
    prep_misc<<<BH / 256, 256, 0, stream>>>(x, h0, c0,
                                            Ap[0], Ap[1], Ap[2], Ap[3], cc);

    const dim3 grid(HID / 64, BATCH / 256);   // (16, 16)
    for (int l = 0; l < NLAY; ++l) {
        gemm_lstm_8ph<<<grid, 512, 0, stream>>>(
            Ap[l], Wb + (size_t)l * NG * KTOT, bias + l * NG,
            cc + (size_t)l * BH, cc + (size_t)l * BH, hT + (size_t)l * BH,
            (l < NLAY - 1) ? Ap[l + 1] : nullptr);
    }

    interleave<<<BH / 256, 256, 0, stream>>>(hT, cc, outH, outC);
}